// Round 8
// baseline (184.938 us; speedup 1.0000x reference)
//
#include <hip/hip_runtime.h>

typedef unsigned short ushort_t;
typedef __attribute__((ext_vector_type(8))) short s8v;      // 8 bf16 bits = MFMA A/B frag
typedef __attribute__((ext_vector_type(2))) unsigned u2v;   // packed 4 bf16 (8B LDS write)
typedef __attribute__((ext_vector_type(4))) float f4;       // float4 / MFMA C/D frag

__device__ __forceinline__ ushort_t f2bf(float x) {      // RNE fp32->bf16
    unsigned u = __builtin_bit_cast(unsigned, x);
    return (ushort_t)((u + 0x7FFFu + ((u >> 16) & 1u)) >> 16);
}
__device__ __forceinline__ unsigned pack_hi16(float lo, float hi) {  // {bf16(hi),bf16(lo)} trunc
    unsigned a = __builtin_bit_cast(unsigned, lo);
    unsigned b = __builtin_bit_cast(unsigned, hi);
    return (a >> 16) | (b & 0xFFFF0000u);
}

// ---- fused pre-pass: blocks 0..2047 K-convert, 2048..3071 V-transpose (unchanged) ----
__global__ __launch_bounds__(256) void prep_kv(const float* __restrict__ K,
                                               const float* __restrict__ V,
                                               ushort_t* __restrict__ Kb,
                                               ushort_t* __restrict__ VT) {
    __shared__ ushort_t T[64 * 72];
    if (blockIdx.x < 2048) {
        const int gid = blockIdx.x * 256 + threadIdx.x;
        const int e = (gid & 7) * 8;
        const int h = (gid >> 3) & 15;
        const int s = (gid >> 7) & 2047;
        const int b = gid >> 18;
        const float* src = K + (((b * 2048 + s) * 16 + h) * 64 + e);
        f4 a = *(const f4*)src;
        f4 c = *(const f4*)(src + 4);
        s8v o;
        #pragma unroll
        for (int j = 0; j < 4; ++j) { o[j] = (short)f2bf(a[j]); o[j + 4] = (short)f2bf(c[j]); }
        *(s8v*)(Kb + (((b * 16 + h) * 2048 + s) * 64 + e)) = o;
    } else {
        const int v = blockIdx.x - 2048;
        const int s0 = (v & 31) * 64;
        const int h  = (v >> 5) & 15;
        const int b  = v >> 9;
        const int t  = threadIdx.x;
        {
            const int srow = t >> 2, dc = (t & 3) * 16;
            const float* src = V + (((b * 2048 + s0 + srow) * 16 + h) * 64 + dc);
            #pragma unroll
            for (int c = 0; c < 4; ++c) {
                f4 vv = *(const f4*)(src + c * 4);
                #pragma unroll
                for (int j = 0; j < 4; ++j) T[(dc + c * 4 + j) * 72 + srow] = f2bf(vv[j]);
            }
        }
        __syncthreads();
        {
            const int d = t >> 2, sq = (t & 3) * 16;
            ushort_t* dst = VT + (((b * 16 + h) * 64 + d) * 2048 + s0 + sq);
            *(s8v*)(dst)     = *(const s8v*)(&T[d * 72 + sq]);
            *(s8v*)(dst + 8) = *(const s8v*)(&T[d * 72 + sq + 8]);
        }
    }
}

// ---------------- main: K LDS-staged, V direct-from-L2 flash attention ----------------
// 512 blocks x 256 thr (4 waves x 32 q-rows = 128-row q-tile). Paired halves
// (pr, 15-pr) -> uniform 34 s-iters/block; 2 blocks/CU co-resident = 2 waves/SIMD.
// K tile double-buffered in LDS (read by all 4 waves); V fragments loaded
// directly from L2-resident VT (issued at iter start, consumed in PV) -- this
// removes V staging + V LDS reads (the largest LDS-pipe consumer in R7).
__global__ __launch_bounds__(256, 2) void fattn_main(
    const float* __restrict__ Q,
    const ushort_t* __restrict__ Kb,
    const ushort_t* __restrict__ VTb,
    float* __restrict__ O)
{
    constexpr float K1 = 0.18033688011112042f;   // 0.125 * log2(e)
    constexpr float SHIFT = 12.0f;               // static softmax shift (no running max)
    __shared__ ushort_t KT[2][64 * 72];          // K tile [s][e], double-buffered
    __shared__ ushort_t P[8][16 * 72];           // per (wave,m): 16 q-rows x 64 s-cols

    const int bx = blockIdx.x;
    const int bh = bx & 31;                      // bh%8 == bx%8 -> 4 bh per XCD
    const int pr = bx >> 5;                      // 0..15 -> q-tile pair (pr, 15-pr)
    const int b = bh >> 4, h = bh & 15;

    const int wave = threadIdx.x >> 6;
    const int lane = threadIdx.x & 63;
    const int l15  = lane & 15;
    const int quad = lane >> 4;

    const ushort_t* kb  = Kb  + bh * (2048 * 64);
    const ushort_t* vtb = VTb + bh * (64 * 2048);
    const float*    qb  = Q + b * (2048 * 1024) + h * 64;
    float*          ob  = O + b * (2048 * 1024) + h * 64;

    const s8v ones = {0x3F80, 0x3F80, 0x3F80, 0x3F80, 0x3F80, 0x3F80, 0x3F80, 0x3F80};
    const f4 zero4 = {0.f, 0.f, 0.f, 0.f};

    // staging coordinates: 256 threads copy the 64x64 K tile (16 elems each)
    const int sr = threadIdx.x >> 2;             // row 0..63
    const int sc = (threadIdx.x & 3) << 4;       // col 0/16/32/48

    for (int half = 0; half < 2; ++half) {
        const int i   = half ? (15 - pr) : pr;   // 128-row q-tile index
        const int qr0 = i * 128;
        const int il  = 2 * i + 1;               // last 64-wide s-tile index

        // Q fragments (fp32 -> bf16): wave's rows qr0 + wave*32 + m*16 + l15
        s8v aq[2][2];
        #pragma unroll
        for (int m = 0; m < 2; ++m) {
            const float* qrow = qb + (qr0 + wave * 32 + m * 16 + l15) * 1024;
            #pragma unroll
            for (int ks = 0; ks < 2; ++ks) {
                f4 x = *(const f4*)(qrow + ks * 32 + quad * 8);
                f4 y = *(const f4*)(qrow + ks * 32 + quad * 8 + 4);
                #pragma unroll
                for (int j = 0; j < 4; ++j) {
                    aq[m][ks][j]     = (short)f2bf(x[j]);
                    aq[m][ks][j + 4] = (short)f2bf(y[j]);
                }
            }
        }

        f4 oacc[2][4];
        f4 lsum[2] = {zero4, zero4};
        #pragma unroll
        for (int m = 0; m < 2; ++m)
            #pragma unroll
            for (int d = 0; d < 4; ++d) oacc[m][d] = zero4;

        // ---- prologue: stage K tile 0 into buffer 0 ----
        {
            const ushort_t* ksrc = kb + sr * 64 + sc;
            *(s8v*)&KT[0][sr * 72 + sc]     = *(const s8v*)(ksrc);
            *(s8v*)&KT[0][sr * 72 + sc + 8] = *(const s8v*)(ksrc + 8);
        }
        __syncthreads();

        for (int it = 0; it <= il; ++it) {
            const int cur = it & 1;
            const int n0  = it * 64;

            // ---- V fragments direct from L2 (issued first, consumed in PV) ----
            const ushort_t* vp = vtb + n0;
            s8v bv[4][2];
            #pragma unroll
            for (int dd = 0; dd < 4; ++dd)
                #pragma unroll
                for (int ks = 0; ks < 2; ++ks)
                    bv[dd][ks] = *(const s8v*)(vp + (dd * 16 + l15) * 2048 + ks * 32 + quad * 8);

            // ---- stage K tile it+1 into the other buffer ----
            if (it < il) {
                const ushort_t* ksrc = kb + ((it + 1) * 64 + sr) * 64 + sc;
                *(s8v*)&KT[cur ^ 1][sr * 72 + sc]     = *(const s8v*)(ksrc);
                *(s8v*)&KT[cur ^ 1][sr * 72 + sc + 8] = *(const s8v*)(ksrc + 8);
            }

            const bool diag = (it >= il - 1);   // last two s-tiles cross the causal edge

            // ---- QK^T (S^T = K*Q^T) with exp interleaved per t-subtile ----
            #pragma unroll
            for (int t = 0; t < 4; ++t) {
                const s8v bk0 = *(const s8v*)&KT[cur][(t * 16 + l15) * 72 + quad * 8];
                const s8v bk1 = *(const s8v*)&KT[cur][(t * 16 + l15) * 72 + 32 + quad * 8];
                #pragma unroll
                for (int m = 0; m < 2; ++m) {
                    f4 a  = __builtin_amdgcn_mfma_f32_16x16x32_bf16(bk0, aq[m][0], zero4, 0, 0, 0);
                    f4 st = __builtin_amdgcn_mfma_f32_16x16x32_bf16(bk1, aq[m][1], a, 0, 0, 0);
                    float p[4];
                    #pragma unroll
                    for (int r = 0; r < 4; ++r) {
                        float x = __builtin_fmaf(st[r], K1, -SHIFT);
                        if (diag) {
                            const int gj = n0 + t * 16 + quad * 4 + r;              // s-col
                            const int gi = qr0 + wave * 32 + m * 16 + l15;          // q-row
                            if (gj > gi) x = -INFINITY;
                        }
                        p[r] = __builtin_exp2f(x);
                    }
                    u2v pk;
                    pk[0] = pack_hi16(p[0], p[1]);
                    pk[1] = pack_hi16(p[2], p[3]);
                    *(u2v*)&P[wave * 2 + m][l15 * 72 + t * 16 + quad * 4] = pk;
                }
            }

            // ---- PV + rowsum-via-ones-MFMA; P from LDS, V from registers ----
            #pragma unroll
            for (int ks = 0; ks < 2; ++ks) {
                #pragma unroll
                for (int m = 0; m < 2; ++m) {
                    const s8v ap = *(const s8v*)&P[wave * 2 + m][l15 * 72 + ks * 32 + quad * 8];
                    lsum[m] = __builtin_amdgcn_mfma_f32_16x16x32_bf16(ap, ones, lsum[m], 0, 0, 0);
                    #pragma unroll
                    for (int dd = 0; dd < 4; ++dd)
                        oacc[m][dd] = __builtin_amdgcn_mfma_f32_16x16x32_bf16(ap, bv[dd][ks], oacc[m][dd], 0, 0, 0);
                }
            }

            __syncthreads();   // staged K(it+1) visible; KT[cur] free for it+2
        }

        // ---- epilogue: waves own disjoint q-rows -> direct store, no merge ----
        #pragma unroll
        for (int m = 0; m < 2; ++m)
            #pragma unroll
            for (int r = 0; r < 4; ++r) {
                const float inv = 1.0f / lsum[m][r];
                const int row = qr0 + wave * 32 + m * 16 + quad * 4 + r;
                #pragma unroll
                for (int dd = 0; dd < 4; ++dd)
                    ob[row * 1024 + dd * 16 + l15] = oacc[m][dd][r] * inv;
            }
    }
}

// ---------------- fallback (R2, known-correct) if workspace too small ----------------
#define PSTR 72
__global__ __launch_bounds__(256) void fattn_fallback(
    const float* __restrict__ Q, const float* __restrict__ K,
    const float* __restrict__ V, float* __restrict__ O)
{
    constexpr int strL = 1024, strB = 2048 * strL;
    const float scale = 0.125f;
    __shared__ ushort_t KT[64 * PSTR];
    __shared__ ushort_t VT[64 * PSTR];
    __shared__ ushort_t P[4][16 * PSTR];
    const int bh = blockIdx.x & 31;
    const int b = bh >> 4, h = bh & 15;
    const int im = 31 - (blockIdx.x >> 5);
    const int q0 = im * 64;
    const int tid = threadIdx.x, wave = tid >> 6, lane = tid & 63;
    const int l15 = lane & 15, quad = lane >> 4;
    const float* qbase = Q + b*strB + (q0 + wave*16 + l15)*strL + h*64;
    s8v aq0, aq1;
    {
        f4 q0v = *(const f4*)(qbase + quad*8);
        f4 q1v = *(const f4*)(qbase + quad*8 + 4);
        f4 q2v = *(const f4*)(qbase + 32 + quad*8);
        f4 q3v = *(const f4*)(qbase + 32 + quad*8 + 4);
        #pragma unroll
        for (int j = 0; j < 4; ++j) {
            aq0[j] = (short)f2bf(q0v[j]); aq0[j+4] = (short)f2bf(q1v[j]);
            aq1[j] = (short)f2bf(q2v[j]); aq1[j+4] = (short)f2bf(q3v[j]);
        }
    }
    const f4 zero4 = {0.f,0.f,0.f,0.f};
    f4 oacc[4]; float m_prev[4], lsum[4];
    #pragma unroll
    for (int d = 0; d < 4; ++d) oacc[d] = zero4;
    #pragma unroll
    for (int r = 0; r < 4; ++r) { m_prev[r] = -INFINITY; lsum[r] = 0.0f; }
    const float* kh = K + b*strB + h*64;
    const float* vh = V + b*strB + h*64;
    for (int it = 0; it <= im; ++it) {
        const int n0 = it * 64;
        __syncthreads();
        {
            const float* krow = kh + (n0 + lane)*strL + wave*16;
            f4 k0 = *(const f4*)(krow); f4 k1 = *(const f4*)(krow+4);
            f4 k2 = *(const f4*)(krow+8); f4 k3 = *(const f4*)(krow+12);
            s8v kb0, kb1;
            #pragma unroll
            for (int j = 0; j < 4; ++j) {
                kb0[j] = (short)f2bf(k0[j]); kb0[j+4] = (short)f2bf(k1[j]);
                kb1[j] = (short)f2bf(k2[j]); kb1[j+4] = (short)f2bf(k3[j]);
            }
            *(s8v*)&KT[lane*PSTR + wave*16] = kb0;
            *(s8v*)&KT[lane*PSTR + wave*16 + 8] = kb1;
            const float* vrow = vh + (n0 + lane)*strL + wave*16;
            f4 v0 = *(const f4*)(vrow); f4 v1 = *(const f4*)(vrow+4);
            f4 v2 = *(const f4*)(vrow+8); f4 v3 = *(const f4*)(vrow+12);
            #pragma unroll
            for (int j = 0; j < 4; ++j) {
                VT[(wave*16 + j)*PSTR + lane] = f2bf(v0[j]);
                VT[(wave*16 + 4 + j)*PSTR + lane] = f2bf(v1[j]);
                VT[(wave*16 + 8 + j)*PSTR + lane] = f2bf(v2[j]);
                VT[(wave*16 + 12 + j)*PSTR + lane] = f2bf(v3[j]);
            }
        }
        __syncthreads();
        f4 sacc[4];
        #pragma unroll
        for (int t = 0; t < 4; ++t) {
            sacc[t] = zero4;
            const s8v bk0 = *(const s8v*)&KT[(t*16 + l15)*PSTR + quad*8];
            const s8v bk1 = *(const s8v*)&KT[(t*16 + l15)*PSTR + 32 + quad*8];
            sacc[t] = __builtin_amdgcn_mfma_f32_16x16x32_bf16(aq0, bk0, sacc[t], 0, 0, 0);
            sacc[t] = __builtin_amdgcn_mfma_f32_16x16x32_bf16(aq1, bk1, sacc[t], 0, 0, 0);
        }
        const bool diag = (it == im);
        float sv[4][4], rmax[4];
        #pragma unroll
        for (int r = 0; r < 4; ++r) rmax[r] = -INFINITY;
        #pragma unroll
        for (int t = 0; t < 4; ++t)
            #pragma unroll
            for (int r = 0; r < 4; ++r) {
                float x = sacc[t][r] * scale;
                if (diag) {
                    const int gi = wave*16 + quad*4 + r;
                    const int gj = t*16 + l15;
                    if (gj > gi) x = -INFINITY;
                }
                sv[t][r] = x; rmax[r] = fmaxf(rmax[r], x);
            }
        #pragma unroll
        for (int off = 8; off >= 1; off >>= 1)
            #pragma unroll
            for (int r = 0; r < 4; ++r)
                rmax[r] = fmaxf(rmax[r], __shfl_xor(rmax[r], off, 64));
        float mnew[4], alpha[4], rsum[4];
        #pragma unroll
        for (int r = 0; r < 4; ++r) {
            mnew[r] = fmaxf(m_prev[r], rmax[r]);
            alpha[r] = __expf(m_prev[r] - mnew[r]);
            m_prev[r] = mnew[r]; rsum[r] = 0.f;
        }
        #pragma unroll
        for (int t = 0; t < 4; ++t)
            #pragma unroll
            for (int r = 0; r < 4; ++r) {
                const float p = __expf(sv[t][r] - mnew[r]);
                rsum[r] += p;
                P[wave][(quad*4 + r)*PSTR + t*16 + l15] = f2bf(p);
            }
        #pragma unroll
        for (int off = 8; off >= 1; off >>= 1)
            #pragma unroll
            for (int r = 0; r < 4; ++r)
                rsum[r] += __shfl_xor(rsum[r], off, 64);
        #pragma unroll
        for (int r = 0; r < 4; ++r) lsum[r] = alpha[r]*lsum[r] + rsum[r];
        #pragma unroll
        for (int d = 0; d < 4; ++d)
            #pragma unroll
            for (int r = 0; r < 4; ++r) oacc[d][r] *= alpha[r];
        #pragma unroll
        for (int ks = 0; ks < 2; ++ks) {
            const s8v ap = *(const s8v*)&P[wave][l15*PSTR + ks*32 + quad*8];
            #pragma unroll
            for (int d = 0; d < 4; ++d) {
                const s8v bvv = *(const s8v*)&VT[(d*16 + l15)*PSTR + ks*32 + quad*8];
                oacc[d] = __builtin_amdgcn_mfma_f32_16x16x32_bf16(ap, bvv, oacc[d], 0, 0, 0);
            }
        }
    }
    float* obase = O + b*strB + h*64;
    #pragma unroll
    for (int r = 0; r < 4; ++r) {
        const float inv = 1.0f / lsum[r];
        const int gi = q0 + wave*16 + quad*4 + r;
        #pragma unroll
        for (int d = 0; d < 4; ++d)
            obase[gi*strL + d*16 + l15] = oacc[d][r] * inv;
    }
}

extern "C" void kernel_launch(void* const* d_in, const int* in_sizes, int n_in,
                              void* d_out, int out_size, void* d_ws, size_t ws_size,
                              hipStream_t stream) {
    const float* Q = (const float*)d_in[0];
    const float* K = (const float*)d_in[1];
    const float* V = (const float*)d_in[2];
    float* O = (float*)d_out;
    const size_t NEED = 2ull * 4194304ull * 2ull;   // Kb + VT, bf16: 16.78 MB
    if (ws_size >= NEED) {
        ushort_t* Kb = (ushort_t*)d_ws;
        ushort_t* VT = Kb + 4194304;
        prep_kv<<<3072, 256, 0, stream>>>(K, V, Kb, VT);
        fattn_main<<<512, 256, 0, stream>>>(Q, Kb, VT, O);
    } else {
        fattn_fallback<<<1024, 256, 0, stream>>>(Q, K, V, O);
    }
}

// Round 9
// 154.698 us; speedup vs baseline: 1.1955x; 1.1955x over previous
//
#include <hip/hip_runtime.h>

typedef unsigned short ushort_t;
typedef __attribute__((ext_vector_type(8))) short s8v;      // 8 bf16 bits = MFMA A/B frag
typedef __attribute__((ext_vector_type(2))) unsigned u2v;   // packed 4 bf16 (8B LDS write)
typedef __attribute__((ext_vector_type(4))) float f4;       // float4 / MFMA C/D frag

__device__ __forceinline__ ushort_t f2bf(float x) {      // RNE fp32->bf16
    unsigned u = __builtin_bit_cast(unsigned, x);
    return (ushort_t)((u + 0x7FFFu + ((u >> 16) & 1u)) >> 16);
}
__device__ __forceinline__ unsigned pack_hi16(float lo, float hi) {  // {bf16(hi),bf16(lo)} trunc
    unsigned a = __builtin_bit_cast(unsigned, lo);
    unsigned b = __builtin_bit_cast(unsigned, hi);
    return (a >> 16) | (b & 0xFFFF0000u);
}

// ---- fused pre-pass: blocks 0..2047 K-convert, 2048..3071 V-transpose (unchanged) ----
__global__ __launch_bounds__(256) void prep_kv(const float* __restrict__ K,
                                               const float* __restrict__ V,
                                               ushort_t* __restrict__ Kb,
                                               ushort_t* __restrict__ VT) {
    __shared__ ushort_t T[64 * 72];
    if (blockIdx.x < 2048) {
        const int gid = blockIdx.x * 256 + threadIdx.x;
        const int e = (gid & 7) * 8;
        const int h = (gid >> 3) & 15;
        const int s = (gid >> 7) & 2047;
        const int b = gid >> 18;
        const float* src = K + (((b * 2048 + s) * 16 + h) * 64 + e);
        f4 a = *(const f4*)src;
        f4 c = *(const f4*)(src + 4);
        s8v o;
        #pragma unroll
        for (int j = 0; j < 4; ++j) { o[j] = (short)f2bf(a[j]); o[j + 4] = (short)f2bf(c[j]); }
        *(s8v*)(Kb + (((b * 16 + h) * 2048 + s) * 64 + e)) = o;
    } else {
        const int v = blockIdx.x - 2048;
        const int s0 = (v & 31) * 64;
        const int h  = (v >> 5) & 15;
        const int b  = v >> 9;
        const int t  = threadIdx.x;
        {
            const int srow = t >> 2, dc = (t & 3) * 16;
            const float* src = V + (((b * 2048 + s0 + srow) * 16 + h) * 64 + dc);
            #pragma unroll
            for (int c = 0; c < 4; ++c) {
                f4 vv = *(const f4*)(src + c * 4);
                #pragma unroll
                for (int j = 0; j < 4; ++j) T[(dc + c * 4 + j) * 72 + srow] = f2bf(vv[j]);
            }
        }
        __syncthreads();
        {
            const int d = t >> 2, sq = (t & 3) * 16;
            ushort_t* dst = VT + (((b * 16 + h) * 64 + d) * 2048 + s0 + sq);
            *(s8v*)(dst)     = *(const s8v*)(&T[d * 72 + sq]);
            *(s8v*)(dst + 8) = *(const s8v*)(&T[d * 72 + sq + 8]);
        }
    }
}

// ---------------- main: LDS flash attention, register-staged pipeline ----------------
// 1024 blocks x 128 thr (2 waves x 32 q-rows = one 64-row q-tile/block).
// Single-buffered K/V^T LDS tile (27 KB -> 4 blocks/CU = 2 waves/SIMD); the next
// tile is prefetched into REGISTERS during compute and ds_written after the tail
// barrier (register double-buffering: staging latency hidden, LDS small).
// Balance: CU n hosts blocks {n, n+256, n+512, n+768} (round-robin dispatch) ->
// q-tile groups {c,c+8,c+16,c+24}; map group->tile i in {c, 31-c, 15-c, 16+c} so
// every CU's total iteration count is exactly 66.
__global__ __launch_bounds__(128, 2) void fattn_main(
    const float* __restrict__ Q,
    const ushort_t* __restrict__ Kb,
    const ushort_t* __restrict__ VTb,
    float* __restrict__ O)
{
    constexpr float K1 = 0.18033688011112042f;   // 0.125 * log2(e)
    constexpr float SHIFT = 12.0f;               // static softmax shift (no running max)
    __shared__ ushort_t KT [64 * 72];            // K tile  [s][e]
    __shared__ ushort_t VTl[64 * 72];            // V^T tile [d][s]
    __shared__ ushort_t P  [4][16 * 72];         // per (wave,m): 16 q-rows x 64 s-cols

    const int bx = blockIdx.x;
    const int bh = bx & 31;                      // bh%8 == bx%8 -> 4 bh per XCD
    const int g  = bx >> 5, c8 = g & 7, j4 = g >> 3;
    const int i  = (j4 == 0) ? c8 : (j4 == 1) ? 31 - c8 : (j4 == 2) ? 15 - c8 : 16 + c8;
    const int b = bh >> 4, h = bh & 15;
    const int qr0 = i * 64;
    const int il  = i;                           // last 64-wide s-tile index

    const int wave = threadIdx.x >> 6;
    const int lane = threadIdx.x & 63;
    const int l15  = lane & 15;
    const int quad = lane >> 4;

    const ushort_t* kb  = Kb  + bh * (2048 * 64);
    const ushort_t* vtb = VTb + bh * (64 * 2048);
    const float*    qb  = Q + b * (2048 * 1024) + h * 64;
    float*          ob  = O + b * (2048 * 1024) + h * 64;

    const s8v ones = {0x3F80, 0x3F80, 0x3F80, 0x3F80, 0x3F80, 0x3F80, 0x3F80, 0x3F80};
    const f4 zero4 = {0.f, 0.f, 0.f, 0.f};

    // staging coordinates: each of 128 threads owns one 32-elem row-half (4 x b128)
    const int sr = (wave << 5) + (lane >> 1);    // row 0..63 (s for K, d for V)
    const int sc = (lane & 1) << 5;              // col 0 or 32

    // Q fragments (fp32 -> bf16): wave's rows qr0 + wave*32 + m*16 + l15
    s8v aq[2][2];
    #pragma unroll
    for (int m = 0; m < 2; ++m) {
        const float* qrow = qb + (qr0 + wave * 32 + m * 16 + l15) * 1024;
        #pragma unroll
        for (int ks = 0; ks < 2; ++ks) {
            f4 x = *(const f4*)(qrow + ks * 32 + quad * 8);
            f4 y = *(const f4*)(qrow + ks * 32 + quad * 8 + 4);
            #pragma unroll
            for (int j = 0; j < 4; ++j) {
                aq[m][ks][j]     = (short)f2bf(x[j]);
                aq[m][ks][j + 4] = (short)f2bf(y[j]);
            }
        }
    }

    f4 oacc[2][4];
    f4 lsum[2] = {zero4, zero4};
    #pragma unroll
    for (int m = 0; m < 2; ++m)
        #pragma unroll
        for (int d = 0; d < 4; ++d) oacc[m][d] = zero4;

    // ---- prologue: load tile 0 into registers ----
    s8v gK[4], gV[4];
    {
        const ushort_t* ksrc = kb + sr * 64 + sc;
        const ushort_t* vsrc = vtb + sr * 2048 + sc;
        #pragma unroll
        for (int c = 0; c < 4; ++c) {
            gK[c] = *(const s8v*)(ksrc + c * 8);
            gV[c] = *(const s8v*)(vsrc + c * 8);
        }
    }

    for (int it = 0; it <= il; ++it) {
        // ---- commit staged registers to LDS, make visible ----
        #pragma unroll
        for (int c = 0; c < 4; ++c) {
            *(s8v*)&KT [sr * 72 + sc + c * 8] = gK[c];
            *(s8v*)&VTl[sr * 72 + sc + c * 8] = gV[c];
        }
        __syncthreads();

        // ---- prefetch tile it+1 into registers (hidden behind compute) ----
        s8v gK2[4], gV2[4];
        if (it < il) {
            const ushort_t* ksrc = kb + ((it + 1) * 64 + sr) * 64 + sc;
            const ushort_t* vsrc = vtb + sr * 2048 + (it + 1) * 64 + sc;
            #pragma unroll
            for (int c = 0; c < 4; ++c) {
                gK2[c] = *(const s8v*)(ksrc + c * 8);
                gV2[c] = *(const s8v*)(vsrc + c * 8);
            }
        }

        const int n0 = it * 64;
        const bool diag = (it == il);

        // ---- QK^T from LDS (S^T = K*Q^T): lane col = q-row, rows = s-cols ----
        f4 st[2][4];
        #pragma unroll
        for (int t = 0; t < 4; ++t) {
            const s8v bk0 = *(const s8v*)&KT[(t * 16 + l15) * 72 + quad * 8];
            const s8v bk1 = *(const s8v*)&KT[(t * 16 + l15) * 72 + 32 + quad * 8];
            #pragma unroll
            for (int m = 0; m < 2; ++m) {
                f4 a = __builtin_amdgcn_mfma_f32_16x16x32_bf16(bk0, aq[m][0], zero4, 0, 0, 0);
                st[m][t] = __builtin_amdgcn_mfma_f32_16x16x32_bf16(bk1, aq[m][1], a, 0, 0, 0);
            }
        }

        // ---- exp2 + pack + P write ----
        #pragma unroll
        for (int m = 0; m < 2; ++m) {
            ushort_t* Pm = P[wave * 2 + m];
            #pragma unroll
            for (int t = 0; t < 4; ++t) {
                float p[4];
                #pragma unroll
                for (int r = 0; r < 4; ++r) {
                    float x = __builtin_fmaf(st[m][t][r], K1, -SHIFT);
                    if (diag) {
                        const int gj = n0 + t * 16 + quad * 4 + r;          // s-col
                        const int gi = qr0 + wave * 32 + m * 16 + l15;      // q-row
                        if (gj > gi) x = -INFINITY;
                    }
                    p[r] = __builtin_exp2f(x);
                }
                u2v pk;
                pk[0] = pack_hi16(p[0], p[1]);
                pk[1] = pack_hi16(p[2], p[3]);
                *(u2v*)&Pm[l15 * 72 + t * 16 + quad * 4] = pk;
            }
        }

        // ---- PV + rowsum-via-ones-MFMA; V frags hoisted (read once per ks) ----
        #pragma unroll
        for (int ks = 0; ks < 2; ++ks) {
            s8v bvv[4];
            #pragma unroll
            for (int dd = 0; dd < 4; ++dd)
                bvv[dd] = *(const s8v*)&VTl[(dd * 16 + l15) * 72 + ks * 32 + quad * 8];
            #pragma unroll
            for (int m = 0; m < 2; ++m) {
                const s8v ap = *(const s8v*)&P[wave * 2 + m][l15 * 72 + ks * 32 + quad * 8];
                lsum[m] = __builtin_amdgcn_mfma_f32_16x16x32_bf16(ap, ones, lsum[m], 0, 0, 0);
                #pragma unroll
                for (int dd = 0; dd < 4; ++dd)
                    oacc[m][dd] = __builtin_amdgcn_mfma_f32_16x16x32_bf16(ap, bvv[dd], oacc[m][dd], 0, 0, 0);
            }
        }

        __syncthreads();   // all reads of KT/VTl done; safe to overwrite next iter

        if (it < il) {
            #pragma unroll
            for (int c = 0; c < 4; ++c) { gK[c] = gK2[c]; gV[c] = gV2[c]; }
        }
    }

    // ---- epilogue: waves own disjoint q-rows -> direct store, no merge ----
    #pragma unroll
    for (int m = 0; m < 2; ++m)
        #pragma unroll
        for (int r = 0; r < 4; ++r) {
            const float inv = 1.0f / lsum[m][r];
            const int row = qr0 + wave * 32 + m * 16 + quad * 4 + r;
            #pragma unroll
            for (int dd = 0; dd < 4; ++dd)
                ob[row * 1024 + dd * 16 + l15] = oacc[m][dd][r] * inv;
        }
}

// ---------------- fallback (R2, known-correct) if workspace too small ----------------
#define PSTR 72
__global__ __launch_bounds__(256) void fattn_fallback(
    const float* __restrict__ Q, const float* __restrict__ K,
    const float* __restrict__ V, float* __restrict__ O)
{
    constexpr int strL = 1024, strB = 2048 * strL;
    const float scale = 0.125f;
    __shared__ ushort_t KT[64 * PSTR];
    __shared__ ushort_t VT[64 * PSTR];
    __shared__ ushort_t P[4][16 * PSTR];
    const int bh = blockIdx.x & 31;
    const int b = bh >> 4, h = bh & 15;
    const int im = 31 - (blockIdx.x >> 5);
    const int q0 = im * 64;
    const int tid = threadIdx.x, wave = tid >> 6, lane = tid & 63;
    const int l15 = lane & 15, quad = lane >> 4;
    const float* qbase = Q + b*strB + (q0 + wave*16 + l15)*strL + h*64;
    s8v aq0, aq1;
    {
        f4 q0v = *(const f4*)(qbase + quad*8);
        f4 q1v = *(const f4*)(qbase + quad*8 + 4);
        f4 q2v = *(const f4*)(qbase + 32 + quad*8);
        f4 q3v = *(const f4*)(qbase + 32 + quad*8 + 4);
        #pragma unroll
        for (int j = 0; j < 4; ++j) {
            aq0[j] = (short)f2bf(q0v[j]); aq0[j+4] = (short)f2bf(q1v[j]);
            aq1[j] = (short)f2bf(q2v[j]); aq1[j+4] = (short)f2bf(q3v[j]);
        }
    }
    const f4 zero4 = {0.f,0.f,0.f,0.f};
    f4 oacc[4]; float m_prev[4], lsum[4];
    #pragma unroll
    for (int d = 0; d < 4; ++d) oacc[d] = zero4;
    #pragma unroll
    for (int r = 0; r < 4; ++r) { m_prev[r] = -INFINITY; lsum[r] = 0.0f; }
    const float* kh = K + b*strB + h*64;
    const float* vh = V + b*strB + h*64;
    for (int it = 0; it <= im; ++it) {
        const int n0 = it * 64;
        __syncthreads();
        {
            const float* krow = kh + (n0 + lane)*strL + wave*16;
            f4 k0 = *(const f4*)(krow); f4 k1 = *(const f4*)(krow+4);
            f4 k2 = *(const f4*)(krow+8); f4 k3 = *(const f4*)(krow+12);
            s8v kb0, kb1;
            #pragma unroll
            for (int j = 0; j < 4; ++j) {
                kb0[j] = (short)f2bf(k0[j]); kb0[j+4] = (short)f2bf(k1[j]);
                kb1[j] = (short)f2bf(k2[j]); kb1[j+4] = (short)f2bf(k3[j]);
            }
            *(s8v*)&KT[lane*PSTR + wave*16] = kb0;
            *(s8v*)&KT[lane*PSTR + wave*16 + 8] = kb1;
            const float* vrow = vh + (n0 + lane)*strL + wave*16;
            f4 v0 = *(const f4*)(vrow); f4 v1 = *(const f4*)(vrow+4);
            f4 v2 = *(const f4*)(vrow+8); f4 v3 = *(const f4*)(vrow+12);
            #pragma unroll
            for (int j = 0; j < 4; ++j) {
                VT[(wave*16 + j)*PSTR + lane] = f2bf(v0[j]);
                VT[(wave*16 + 4 + j)*PSTR + lane] = f2bf(v1[j]);
                VT[(wave*16 + 8 + j)*PSTR + lane] = f2bf(v2[j]);
                VT[(wave*16 + 12 + j)*PSTR + lane] = f2bf(v3[j]);
            }
        }
        __syncthreads();
        f4 sacc[4];
        #pragma unroll
        for (int t = 0; t < 4; ++t) {
            sacc[t] = zero4;
            const s8v bk0 = *(const s8v*)&KT[(t*16 + l15)*PSTR + quad*8];
            const s8v bk1 = *(const s8v*)&KT[(t*16 + l15)*PSTR + 32 + quad*8];
            sacc[t] = __builtin_amdgcn_mfma_f32_16x16x32_bf16(aq0, bk0, sacc[t], 0, 0, 0);
            sacc[t] = __builtin_amdgcn_mfma_f32_16x16x32_bf16(aq1, bk1, sacc[t], 0, 0, 0);
        }
        const bool diag = (it == im);
        float sv[4][4], rmax[4];
        #pragma unroll
        for (int r = 0; r < 4; ++r) rmax[r] = -INFINITY;
        #pragma unroll
        for (int t = 0; t < 4; ++t)
            #pragma unroll
            for (int r = 0; r < 4; ++r) {
                float x = sacc[t][r] * scale;
                if (diag) {
                    const int gi = wave*16 + quad*4 + r;
                    const int gj = t*16 + l15;
                    if (gj > gi) x = -INFINITY;
                }
                sv[t][r] = x; rmax[r] = fmaxf(rmax[r], x);
            }
        #pragma unroll
        for (int off = 8; off >= 1; off >>= 1)
            #pragma unroll
            for (int r = 0; r < 4; ++r)
                rmax[r] = fmaxf(rmax[r], __shfl_xor(rmax[r], off, 64));
        float mnew[4], alpha[4], rsum[4];
        #pragma unroll
        for (int r = 0; r < 4; ++r) {
            mnew[r] = fmaxf(m_prev[r], rmax[r]);
            alpha[r] = __expf(m_prev[r] - mnew[r]);
            m_prev[r] = mnew[r]; rsum[r] = 0.f;
        }
        #pragma unroll
        for (int t = 0; t < 4; ++t)
            #pragma unroll
            for (int r = 0; r < 4; ++r) {
                const float p = __expf(sv[t][r] - mnew[r]);
                rsum[r] += p;
                P[wave][(quad*4 + r)*PSTR + t*16 + l15] = f2bf(p);
            }
        #pragma unroll
        for (int off = 8; off >= 1; off >>= 1)
            #pragma unroll
            for (int r = 0; r < 4; ++r)
                rsum[r] += __shfl_xor(rsum[r], off, 64);
        #pragma unroll
        for (int r = 0; r < 4; ++r) lsum[r] = alpha[r]*lsum[r] + rsum[r];
        #pragma unroll
        for (int d = 0; d < 4; ++d)
            #pragma unroll
            for (int r = 0; r < 4; ++r) oacc[d][r] *= alpha[r];
        #pragma unroll
        for (int ks = 0; ks < 2; ++ks) {
            const s8v ap = *(const s8v*)&P[wave][l15*PSTR + ks*32 + quad*8];
            #pragma unroll
            for (int d = 0; d < 4; ++d) {
                const s8v bvv = *(const s8v*)&VT[(d*16 + l15)*PSTR + ks*32 + quad*8];
                oacc[d] = __builtin_amdgcn_mfma_f32_16x16x32_bf16(ap, bvv, oacc[d], 0, 0, 0);
            }
        }
    }
    float* obase = O + b*strB + h*64;
    #pragma unroll
    for (int r = 0; r < 4; ++r) {
        const float inv = 1.0f / lsum[r];
        const int gi = q0 + wave*16 + quad*4 + r;
        #pragma unroll
        for (int d = 0; d < 4; ++d)
            obase[gi*strL + d*16 + l15] = oacc[d][r] * inv;
    }
}

extern "C" void kernel_launch(void* const* d_in, const int* in_sizes, int n_in,
                              void* d_out, int out_size, void* d_ws, size_t ws_size,
                              hipStream_t stream) {
    const float* Q = (const float*)d_in[0];
    const float* K = (const float*)d_in[1];
    const float* V = (const float*)d_in[2];
    float* O = (float*)d_out;
    const size_t NEED = 2ull * 4194304ull * 2ull;   // Kb + VT, bf16: 16.78 MB
    if (ws_size >= NEED) {
        ushort_t* Kb = (ushort_t*)d_ws;
        ushort_t* VT = Kb + 4194304;
        prep_kv<<<3072, 256, 0, stream>>>(K, V, Kb, VT);
        fattn_main<<<1024, 128, 0, stream>>>(Q, Kb, VT, O);
    } else {
        fattn_fallback<<<1024, 256, 0, stream>>>(Q, K, V, O);
    }
}